// Round 6
// baseline (249.358 us; speedup 1.0000x reference)
//
#include <hip/hip_runtime.h>
#include <hip/hip_bf16.h>

// RelationNet fused pipeline, fp32 in/out, ONE persistent kernel + custom grid barrier.
// B=4 Q=256 S=128 C=256; feats 512 -> 256 -> 64 -> 1; BN (training) + ReLU each layer.
//
// Factorization: concat(uq,us)@W0^T = query@W0a^T + support@W0b^T => Aq[b,q,o], As[b,s,o]
// (b0 folded into As). BN0 stats analytic from per-b sums:
//   sum  y0 = S*sum(Aq) + Q*sum(As)
//   sum y0^2 = S*sum(Aq^2) + Q*sum(As^2) + 2*sum_b (sum_q Aq[b])·(sum_s As[b])
// GEMM0 ~fp32 via 3-term hi/lo bf16 split; GEMM1 z-side bf16-RNE, W1-side hi/lo split.
// Grid barrier: release fetch_add + relaxed spin + acquire (agent scope) — no coop API.

typedef __attribute__((ext_vector_type(4))) float f32x4;
typedef __attribute__((ext_vector_type(8))) short s16x8;

#define BN_EPS 1e-5f
#define INV_N  (1.0f/131072.0f)
#define NBLK   256

__device__ __forceinline__ unsigned pk_bf16(float a, float b) {
  float2 t; t.x = a; t.y = b;
  __hip_bfloat162 h = __float22bfloat162_rn(t);
  return *reinterpret_cast<unsigned*>(&h);
}
__device__ __forceinline__ void split2(float a, float b, unsigned& uh, unsigned& ul) {
  uh = pk_bf16(a, b);
  float ha = __uint_as_float(uh << 16);
  float hb = __uint_as_float(uh & 0xFFFF0000u);
  ul = pk_bf16(a - ha, b - hb);
}
__device__ __forceinline__ unsigned splitbf(float v) {
  unsigned u = __float_as_uint(v);
  unsigned hi = u >> 16;
  float r = v - __uint_as_float(u & 0xFFFF0000u);
  unsigned lo = __float_as_uint(r) >> 16;
  return (hi << 16) | lo;
}

union frag_u { s16x8 v; unsigned u[4]; };

struct Args {
  const float *Sf, *Qf, *W0, *b0, *g0, *bt0, *W1, *b1, *g1, *bt1, *W2, *b2, *g2, *bt2;
  float *Aq, *As, *y2, *ws0p, *ws1f, *ws2f, *out;
  ushort *W0h, *W0l, *W1h, *W1l;
  unsigned *bar;
};

// Grid barrier: per-wave vmcnt drain at __syncthreads, then t0: agent-release
// arrive (L2 writeback per gfx94x/gfx950 memory model), relaxed spin (no
// repeated cache-inv), one acquire load on exit (L1/L2 invalidate).
__device__ __forceinline__ void gridbar(unsigned* bar, int id) {
  __syncthreads();
  if (threadIdx.x == 0) {
    __threadfence();
    __hip_atomic_fetch_add(&bar[id], 1u, __ATOMIC_RELEASE, __HIP_MEMORY_SCOPE_AGENT);
    while (__hip_atomic_load(&bar[id], __ATOMIC_RELAXED, __HIP_MEMORY_SCOPE_AGENT) < NBLK)
      __builtin_amdgcn_s_sleep(2);
    (void)__hip_atomic_load(&bar[id], __ATOMIC_ACQUIRE, __HIP_MEMORY_SCOPE_AGENT);
  }
  __syncthreads();
}

__global__ __launch_bounds__(256) void k_zero(
    float* __restrict__ ws0p, float* __restrict__ ws1f,
    float* __restrict__ ws2f, unsigned* __restrict__ bar)
{
  int t = threadIdx.x;
  for (int i = t; i < 4096; i += 256) ws0p[i] = 0.0f;
  if (t < 128) ws1f[t] = 0.0f;
  if (t < 2)   ws2f[t] = 0.0f;
  if (t < 8)   bar[t] = 0u;
}

// Main-GEMM K-loop (layer-1): z0 generated in bf16-RNE A-frag layout in regs;
// y1 tile = z0 @ W1^T via MFMA (W1 hi/lo split, 2 MFMA/tile).
// Mapping: q = qt*16 + w*4 + mt; A-frag m(lane&15) = s-in-tile; k = channel.
// D: col(lane&15) = j, row(quad*4+r) = s-in-tile.
__device__ __forceinline__ void mfma_kloop(
    const float* __restrict__ Aq, const float* __restrict__ As,
    const float* sh_a0c0, const ushort* __restrict__ W1h,
    const ushort* __restrict__ W1l,
    int b, int qt, int st, int w, int l15, int quad, f32x4 acc[4][4])
{
  const float* asrow = As + ((b << 7) + st * 16 + l15) * 256;
  const float* aqrow[4];
#pragma unroll
  for (int mt = 0; mt < 4; mt++)
    aqrow[mt] = Aq + ((b << 8) + qt * 16 + w * 4 + mt) * 256;

#pragma unroll
  for (int ko = 0; ko < 256; ko += 32) {
    int obase = ko + quad * 8;
    f32x4 a0v0 = *(const f32x4*)(sh_a0c0 + obase);
    f32x4 a0v1 = *(const f32x4*)(sh_a0c0 + obase + 4);
    f32x4 c0v0 = *(const f32x4*)(sh_a0c0 + 256 + obase);
    f32x4 c0v1 = *(const f32x4*)(sh_a0c0 + 256 + obase + 4);
    f32x4 as0 = *(const f32x4*)(asrow + obase);
    f32x4 as1 = *(const f32x4*)(asrow + obase + 4);

    s16x8 zh[4];
#pragma unroll
    for (int mt = 0; mt < 4; mt++) {
      f32x4 aq0 = *(const f32x4*)(aqrow[mt] + obase);
      f32x4 aq1 = *(const f32x4*)(aqrow[mt] + obase + 4);
      f32x4 z0 = (aq0 + as0) * a0v0 + c0v0;
      f32x4 z1 = (aq1 + as1) * a0v1 + c0v1;
      frag_u zz;
      zz.u[0] = pk_bf16(fmaxf(z0[0], 0.0f), fmaxf(z0[1], 0.0f));
      zz.u[1] = pk_bf16(fmaxf(z0[2], 0.0f), fmaxf(z0[3], 0.0f));
      zz.u[2] = pk_bf16(fmaxf(z1[0], 0.0f), fmaxf(z1[1], 0.0f));
      zz.u[3] = pk_bf16(fmaxf(z1[2], 0.0f), fmaxf(z1[3], 0.0f));
      zh[mt] = zz.v;
    }
#pragma unroll
    for (int nt = 0; nt < 4; nt++) {
      int off = (nt * 16 + l15) * 256 + obase;
      s16x8 bh = *(const s16x8*)(W1h + off);
      s16x8 bl = *(const s16x8*)(W1l + off);
#pragma unroll
      for (int mt = 0; mt < 4; mt++) {
        acc[mt][nt] = __builtin_amdgcn_mfma_f32_16x16x32_bf16(zh[mt], bh, acc[mt][nt], 0, 0, 0);
        acc[mt][nt] = __builtin_amdgcn_mfma_f32_16x16x32_bf16(zh[mt], bl, acc[mt][nt], 0, 0, 0);
      }
    }
  }
}

__global__ __launch_bounds__(256, 2) void k_all(Args a)
{
  int bi = blockIdx.x, t = threadIdx.x;
  int w = t >> 6, l = t & 63, l15 = l & 15, quad = l >> 4;

  __shared__ float sh_a0c0[512];
  __shared__ float red[2][4][4][16];
  __shared__ float sh_a1c1[128];
  __shared__ float rs[16], rs2[16];

  // ================= P0: split W0/W1 to hi/lo bf16
  {
    int g0i = bi * 256 + t;  // 65536 threads; W0 has 131072 elems
#pragma unroll
    for (int c = 0; c < 2; c++) {
      int idx = g0i + c * 65536;
      unsigned p = splitbf(a.W0[idx]);
      a.W0h[idx] = (ushort)(p >> 16); a.W0l[idx] = (ushort)(p & 0xFFFFu);
    }
    if (g0i < 16384) {
      unsigned q = splitbf(a.W1[g0i]);
      a.W1h[g0i] = (ushort)(q >> 16); a.W1l[g0i] = (ushort)(q & 0xFFFFu);
    }
  }
  gridbar(a.bar, 0);

  // ================= P1: gemm0 — Aq = Q@W0a^T ; As = S@W0b^T + b0 (384 wave-tiles)
  // ws0p: [0:1024) sumAq[b][o], [1024:2048) sumsqAq, [2048:3072) sumAs, [3072:4096) sumsqAs
  {
    int gw = bi * 4 + w;
    if (gw < 384) {
      int mtile = gw >> 2, ntile = gw & 3;
      bool isQ = (mtile < 64);
      const float* X; float* Out; int m0, koff, b;
      if (isQ) { m0 = mtile * 16; X = a.Qf; Out = a.Aq; koff = 0; b = m0 >> 8; }
      else     { m0 = (mtile - 64) * 16; X = a.Sf; Out = a.As; koff = 256; b = m0 >> 7; }
      int n0 = ntile * 64;

      f32x4 acc[4] = {};
#pragma unroll
      for (int ko = 0; ko < 256; ko += 32) {
        const float* row = X + (m0 + l15) * 256 + ko + quad * 8;
        f32x4 v0 = *(const f32x4*)(row);
        f32x4 v1 = *(const f32x4*)(row + 4);
        frag_u ah, al;
#pragma unroll
        for (int j = 0; j < 2; j++) {
          split2(v0[2 * j], v0[2 * j + 1], ah.u[j], al.u[j]);
          split2(v1[2 * j], v1[2 * j + 1], ah.u[2 + j], al.u[2 + j]);
        }
#pragma unroll
        for (int nt = 0; nt < 4; nt++) {
          int off = (n0 + nt * 16 + l15) * 512 + koff + ko + quad * 8;
          s16x8 bh = *(const s16x8*)(a.W0h + off);
          s16x8 bl = *(const s16x8*)(a.W0l + off);
          acc[nt] = __builtin_amdgcn_mfma_f32_16x16x32_bf16(ah.v, bh, acc[nt], 0, 0, 0);
          acc[nt] = __builtin_amdgcn_mfma_f32_16x16x32_bf16(al.v, bh, acc[nt], 0, 0, 0);
          acc[nt] = __builtin_amdgcn_mfma_f32_16x16x32_bf16(ah.v, bl, acc[nt], 0, 0, 0);
        }
      }
#pragma unroll
      for (int nt = 0; nt < 4; nt++) {
        int o = n0 + nt * 16 + l15;
        float bias = isQ ? 0.0f : a.b0[o];
        float cs = 0, cs2 = 0;
#pragma unroll
        for (int r = 0; r < 4; r++) {
          float y = acc[nt][r] + bias;
          Out[(m0 + quad * 4 + r) * 256 + o] = y;
          cs += y; cs2 += y * y;
        }
        cs  += __shfl_xor(cs, 16);  cs  += __shfl_xor(cs, 32);
        cs2 += __shfl_xor(cs2, 16); cs2 += __shfl_xor(cs2, 32);
        if (quad == 0) {
          int base = isQ ? 0 : 2048;
          atomicAdd(&a.ws0p[base + b * 256 + o], cs);
          atomicAdd(&a.ws0p[base + 1024 + b * 256 + o], cs2);
        }
      }
    }
  }
  gridbar(a.bar, 1);

  // ================= P2: redundant BN0 finalize -> LDS; main pass 1 (BN1 stats), 2 tiles
  {
    int o = t;
    float sumY = 0, cross = 0, SQ2 = 0, SS2 = 0;
#pragma unroll
    for (int b = 0; b < 4; b++) {
      float sq1 = a.ws0p[b * 256 + o];
      float ss1 = a.ws0p[2048 + b * 256 + o];
      SQ2 += a.ws0p[1024 + b * 256 + o];
      SS2 += a.ws0p[3072 + b * 256 + o];
      sumY += 128.0f * sq1 + 256.0f * ss1;
      cross += sq1 * ss1;
    }
    float mean = sumY * INV_N;
    float var = (128.0f * SQ2 + 256.0f * SS2 + 2.0f * cross) * INV_N - mean * mean;
    float aa = a.g0[o] * rsqrtf(var + BN_EPS);
    sh_a0c0[o] = aa;
    sh_a0c0[256 + o] = a.bt0[o] - mean * aa;
  }
  __syncthreads();

  for (int T = bi; T < 512; T += NBLK) {
    int b_ = T >> 7, rem = T & 127, qt = rem >> 3, st = rem & 7;
    f32x4 acc[4][4] = {};
    mfma_kloop(a.Aq, a.As, sh_a0c0, a.W1h, a.W1l, b_, qt, st, w, l15, quad, acc);

#pragma unroll
    for (int nt = 0; nt < 4; nt++) {
      float bias = a.b1[nt * 16 + l15];
      float s = 0, s2 = 0;
#pragma unroll
      for (int mt = 0; mt < 4; mt++)
#pragma unroll
        for (int r = 0; r < 4; r++) {
          float y = acc[mt][nt][r] + bias;
          s += y; s2 += y * y;
        }
      s  += __shfl_xor(s, 16);  s  += __shfl_xor(s, 32);
      s2 += __shfl_xor(s2, 16); s2 += __shfl_xor(s2, 32);
      if (quad == 0) { red[0][w][nt][l15] = s; red[1][w][nt][l15] = s2; }
    }
    __syncthreads();
    if (t < 128) {
      int which = t >> 6, j = t & 63, nt = j >> 4, jl = j & 15;
      float v = red[which][0][nt][jl] + red[which][1][nt][jl] +
                red[which][2][nt][jl] + red[which][3][nt][jl];
      atomicAdd(&a.ws1f[t], v);  // t<64: sum[j], t>=64: sumsq[j]
    }
    __syncthreads();
  }
  gridbar(a.bar, 2);

  // ================= P3: redundant BN1 finalize -> LDS; main pass 2 (y2 + BN2 stats)
  if (t < 64) {
    float mean = a.ws1f[t] * INV_N;
    float var = a.ws1f[64 + t] * INV_N - mean * mean;
    float aa = a.g1[t] * rsqrtf(var + BN_EPS);
    sh_a1c1[t] = aa;
    sh_a1c1[64 + t] = a.bt1[t] - mean * aa;
  }
  __syncthreads();

  for (int T = bi; T < 512; T += NBLK) {
    int b_ = T >> 7, rem = T & 127, qt = rem >> 3, st = rem & 7;
    f32x4 acc[4][4] = {};
    mfma_kloop(a.Aq, a.As, sh_a0c0, a.W1h, a.W1l, b_, qt, st, w, l15, quad, acc);

    float a1v[4], c1v[4], w2v[4], biasv[4];
#pragma unroll
    for (int nt = 0; nt < 4; nt++) {
      int j = nt * 16 + l15;
      a1v[nt] = sh_a1c1[j]; c1v[nt] = sh_a1c1[64 + j];
      w2v[nt] = a.W2[j]; biasv[nt] = a.b1[j];
    }
    float b2v = a.b2[0];
    float ls = 0, ls2 = 0;
#pragma unroll
    for (int mt = 0; mt < 4; mt++) {
      float part[4] = {0, 0, 0, 0};
#pragma unroll
      for (int nt = 0; nt < 4; nt++)
#pragma unroll
        for (int r = 0; r < 4; r++) {
          float y = acc[mt][nt][r] + biasv[nt];
          float z = fmaxf(a1v[nt] * y + c1v[nt], 0.0f);
          part[r] += z * w2v[nt];
        }
#pragma unroll
      for (int r = 0; r < 4; r++) {
        float p = part[r];
        p += __shfl_xor(p, 1); p += __shfl_xor(p, 2);
        p += __shfl_xor(p, 4); p += __shfl_xor(p, 8);
        part[r] = p + b2v;
      }
      if (l15 == 0) {
        int q = qt * 16 + w * 4 + mt;
        int P = ((b_ * 256 + q) * 128) + st * 16 + quad * 4;
        f32x4 o;
#pragma unroll
        for (int r = 0; r < 4; r++) { o[r] = part[r]; ls += part[r]; ls2 += part[r] * part[r]; }
        *(f32x4*)(a.y2 + P) = o;
      }
    }
    if (l15 == 0) { rs[t >> 4] = ls; rs2[t >> 4] = ls2; }
    __syncthreads();
    if (t == 0) {
      float s = 0, s2 = 0;
#pragma unroll
      for (int i = 0; i < 16; i++) { s += rs[i]; s2 += rs2[i]; }
      atomicAdd(&a.ws2f[0], s); atomicAdd(&a.ws2f[1], s2);
    }
    __syncthreads();
  }
  gridbar(a.bar, 3);

  // ================= P4: out[P] = relu(a2*y2[P] + c2), a2c2 computed per-thread
  {
    int gtid = bi * 256 + t;
    if (gtid < 32768) {
      float s = a.ws2f[0], s2 = a.ws2f[1];
      float mean = s * INV_N;
      float var = s2 * INV_N - mean * mean;
      float aa = a.g2[0] * rsqrtf(var + BN_EPS);
      float cc = a.bt2[0] - mean * aa;
      f32x4 v = *(const f32x4*)(a.y2 + gtid * 4);
      f32x4 o;
#pragma unroll
      for (int r = 0; r < 4; r++) o[r] = fmaxf(aa * v[r] + cc, 0.0f);
      *(f32x4*)(a.out + gtid * 4) = o;
    }
  }
}

extern "C" void kernel_launch(void* const* d_in, const int* in_sizes, int n_in,
                              void* d_out, int out_size, void* d_ws, size_t ws_size,
                              hipStream_t stream)
{
  float* ws = (float*)d_ws;
  Args a;
  a.Sf  = (const float*)d_in[0];   // support [4,128,256]
  a.Qf  = (const float*)d_in[1];   // query   [4,256,256]
  a.W0  = (const float*)d_in[2];   // [256,512]
  a.b0  = (const float*)d_in[3];
  a.g0  = (const float*)d_in[4];
  a.bt0 = (const float*)d_in[5];
  a.W1  = (const float*)d_in[6];   // [64,256]
  a.b1  = (const float*)d_in[7];
  a.g1  = (const float*)d_in[8];
  a.bt1 = (const float*)d_in[9];
  a.W2  = (const float*)d_in[10];  // [1,64]
  a.b2  = (const float*)d_in[11];
  a.g2  = (const float*)d_in[12];
  a.bt2 = (const float*)d_in[13];

  a.Aq   = ws;                       // 262144 f
  a.As   = ws + 262144;              // 131072 f
  a.y2   = ws + 393216;              // 131072 f
  a.ws0p = ws + 524288;              // 4096 f
  a.ws1f = ws + 528384;              // 128 f
  a.ws2f = ws + 528512;              // 2 f
  a.bar  = (unsigned*)(ws + 528516); // 8 u32
  a.W0h  = (ushort*)(ws + 528640);   // 131072 u16 = 65536 f
  a.W0l  = (ushort*)(ws + 594176);   // 131072 u16
  a.W1h  = (ushort*)(ws + 659712);   // 16384 u16 = 8192 f
  a.W1l  = (ushort*)(ws + 667904);   // 16384 u16 -> total ~2.7 MB
  a.out  = (float*)d_out;

  k_zero<<<1, 256, 0, stream>>>(a.ws0p, a.ws1f, a.ws2f, a.bar);
  k_all<<<NBLK, 256, 0, stream>>>(a);
}

// Round 7
// 187.741 us; speedup vs baseline: 1.3282x; 1.3282x over previous
//
#include <hip/hip_runtime.h>
#include <hip/hip_bf16.h>

// RelationNet fused pipeline, fp32 in/out: k_prep + ONE persistent kernel.
// B=4 Q=256 S=128 C=256; feats 512 -> 256 -> 64 -> 1; BN (training) + ReLU each layer.
//
// Factorization: concat(uq,us)@W0^T = query@W0a^T + support@W0b^T => Aq[b,q,o], As[b,s,o]
// (b0 folded into As). BN0 stats analytic from per-b sums:
//   sum  y0 = S*sum(Aq) + Q*sum(As)
//   sum y0^2 = S*sum(Aq^2) + Q*sum(As^2) + 2*sum_b (sum_q Aq[b])·(sum_s As[b])
// GEMM0 ~fp32 via 3-term hi/lo bf16 split; GEMM1 z-side bf16-RNE, W1-side hi/lo split.
// R6 lesson: 512-way same-address atomicAdd + flat 256-arrival barriers = 150us stall.
// Now: per-block slot writes + redundant post-barrier reduce; hierarchical barrier.

typedef __attribute__((ext_vector_type(4))) float f32x4;
typedef __attribute__((ext_vector_type(8))) short s16x8;

#define BN_EPS 1e-5f
#define INV_N  (1.0f/131072.0f)
#define NBLK   256

__device__ __forceinline__ unsigned pk_bf16(float a, float b) {
  float2 t; t.x = a; t.y = b;
  __hip_bfloat162 h = __float22bfloat162_rn(t);
  return *reinterpret_cast<unsigned*>(&h);
}
__device__ __forceinline__ void split2(float a, float b, unsigned& uh, unsigned& ul) {
  uh = pk_bf16(a, b);
  float ha = __uint_as_float(uh << 16);
  float hb = __uint_as_float(uh & 0xFFFF0000u);
  ul = pk_bf16(a - ha, b - hb);
}
__device__ __forceinline__ unsigned splitbf(float v) {
  unsigned u = __float_as_uint(v);
  unsigned hi = u >> 16;
  float r = v - __uint_as_float(u & 0xFFFF0000u);
  unsigned lo = __float_as_uint(r) >> 16;
  return (hi << 16) | lo;
}

union frag_u { s16x8 v; unsigned u[4]; };

struct Args {
  const float *Sf, *Qf, *W0, *b0, *g0, *bt0, *W1, *b1, *g1, *bt1, *W2, *b2, *g2, *bt2;
  float *Aq, *As, *y2, *ws0p, *ws1p, *ws2p, *out;
  ushort *W0h, *W0l, *W1h, *W1l;
  unsigned *bar;
};

// Hierarchical grid barrier: 32 group counters (8 arrivals each) -> root (32).
// One threadfence (agent release), relaxed adds, read-only root polling,
// single acquire load on exit (L1/L2 inv for cross-XCD visibility).
__device__ __forceinline__ void gridbar(unsigned* bar, int ph) {
  __syncthreads();
  if (threadIdx.x == 0) {
    unsigned* g = bar + ph * 64;   // [0..31] groups, [32] root
    __threadfence();
    unsigned r = __hip_atomic_fetch_add(&g[blockIdx.x >> 3], 1u,
                                        __ATOMIC_RELAXED, __HIP_MEMORY_SCOPE_AGENT);
    if (r == 7)
      __hip_atomic_fetch_add(&g[32], 1u, __ATOMIC_RELAXED, __HIP_MEMORY_SCOPE_AGENT);
    while (__hip_atomic_load(&g[32], __ATOMIC_RELAXED, __HIP_MEMORY_SCOPE_AGENT) < 32u)
      __builtin_amdgcn_s_sleep(8);
    (void)__hip_atomic_load(&g[32], __ATOMIC_ACQUIRE, __HIP_MEMORY_SCOPE_AGENT);
  }
  __syncthreads();
}

// Dispatch 1: split W0/W1 into hi/lo bf16; zero ws0p + barrier counters.
// blocks 0..127: W0 (1024 elems each); blocks 64..127 also W1 (256 each);
// block 128: zero ws0p[4096] + bar[256].
__global__ __launch_bounds__(256) void k_prep(
    const float* __restrict__ W0, const float* __restrict__ W1,
    ushort* __restrict__ W0h, ushort* __restrict__ W0l,
    ushort* __restrict__ W1h, ushort* __restrict__ W1l,
    float* __restrict__ ws0p, unsigned* __restrict__ bar)
{
  int bi = blockIdx.x, t = threadIdx.x;
  if (bi == 128) {
    for (int i = t; i < 4096; i += 256) ws0p[i] = 0.0f;
    if (t < 256) bar[t] = 0u;
    return;
  }
#pragma unroll
  for (int k = 0; k < 4; k++) {
    int idx = bi * 1024 + k * 256 + t;
    unsigned p = splitbf(W0[idx]);
    W0h[idx] = (ushort)(p >> 16); W0l[idx] = (ushort)(p & 0xFFFFu);
  }
  if (bi >= 64) {
    int idx = (bi - 64) * 256 + t;
    unsigned q = splitbf(W1[idx]);
    W1h[idx] = (ushort)(q >> 16); W1l[idx] = (ushort)(q & 0xFFFFu);
  }
}

// Main-GEMM K-loop (layer-1): z0 generated in bf16-RNE A-frag layout in regs;
// y1 tile = z0 @ W1^T via MFMA (W1 hi/lo split, 2 MFMA/tile).
// Mapping: q = qt*16 + w*4 + mt; A-frag m(lane&15) = s-in-tile; k = channel.
// D: col(lane&15) = j, row(quad*4+r) = s-in-tile.
__device__ __forceinline__ void mfma_kloop(
    const float* __restrict__ Aq, const float* __restrict__ As,
    const float* sh_a0c0, const ushort* __restrict__ W1h,
    const ushort* __restrict__ W1l,
    int b, int qt, int st, int w, int l15, int quad, f32x4 acc[4][4])
{
  const float* asrow = As + ((b << 7) + st * 16 + l15) * 256;
  const float* aqrow[4];
#pragma unroll
  for (int mt = 0; mt < 4; mt++)
    aqrow[mt] = Aq + ((b << 8) + qt * 16 + w * 4 + mt) * 256;

#pragma unroll
  for (int ko = 0; ko < 256; ko += 32) {
    int obase = ko + quad * 8;
    f32x4 a0v0 = *(const f32x4*)(sh_a0c0 + obase);
    f32x4 a0v1 = *(const f32x4*)(sh_a0c0 + obase + 4);
    f32x4 c0v0 = *(const f32x4*)(sh_a0c0 + 256 + obase);
    f32x4 c0v1 = *(const f32x4*)(sh_a0c0 + 256 + obase + 4);
    f32x4 as0 = *(const f32x4*)(asrow + obase);
    f32x4 as1 = *(const f32x4*)(asrow + obase + 4);

    s16x8 zh[4];
#pragma unroll
    for (int mt = 0; mt < 4; mt++) {
      f32x4 aq0 = *(const f32x4*)(aqrow[mt] + obase);
      f32x4 aq1 = *(const f32x4*)(aqrow[mt] + obase + 4);
      f32x4 z0 = (aq0 + as0) * a0v0 + c0v0;
      f32x4 z1 = (aq1 + as1) * a0v1 + c0v1;
      frag_u zz;
      zz.u[0] = pk_bf16(fmaxf(z0[0], 0.0f), fmaxf(z0[1], 0.0f));
      zz.u[1] = pk_bf16(fmaxf(z0[2], 0.0f), fmaxf(z0[3], 0.0f));
      zz.u[2] = pk_bf16(fmaxf(z1[0], 0.0f), fmaxf(z1[1], 0.0f));
      zz.u[3] = pk_bf16(fmaxf(z1[2], 0.0f), fmaxf(z1[3], 0.0f));
      zh[mt] = zz.v;
    }
#pragma unroll
    for (int nt = 0; nt < 4; nt++) {
      int off = (nt * 16 + l15) * 256 + obase;
      s16x8 bh = *(const s16x8*)(W1h + off);
      s16x8 bl = *(const s16x8*)(W1l + off);
#pragma unroll
      for (int mt = 0; mt < 4; mt++) {
        acc[mt][nt] = __builtin_amdgcn_mfma_f32_16x16x32_bf16(zh[mt], bh, acc[mt][nt], 0, 0, 0);
        acc[mt][nt] = __builtin_amdgcn_mfma_f32_16x16x32_bf16(zh[mt], bl, acc[mt][nt], 0, 0, 0);
      }
    }
  }
}

__global__ __launch_bounds__(256, 2) void k_all(Args a)
{
  int bi = blockIdx.x, t = threadIdx.x;
  int w = t >> 6, l = t & 63, l15 = l & 15, quad = l >> 4;

  __shared__ float sh_a0c0[512];
  __shared__ float red[2][4][4][16];
  __shared__ float sh_s1[128];
  __shared__ float sh_tot[128];
  __shared__ float sh_a1c1[128];
  __shared__ float rs[16], rs2[16];
  __shared__ float sh_r[256], sh_q[256];

  // ================= P1: gemm0 — Aq = Q@W0a^T ; As = S@W0b^T + b0 (384 wave-tiles)
  // ws0p: [0:1024) sumAq[b][o], [1024:2048) sumsqAq, [2048:3072) sumAs, [3072:4096) sumsqAs
  {
    int gw = bi * 4 + w;
    if (gw < 384) {
      int mtile = gw >> 2, ntile = gw & 3;
      bool isQ = (mtile < 64);
      const float* X; float* Out; int m0, koff, b;
      if (isQ) { m0 = mtile * 16; X = a.Qf; Out = a.Aq; koff = 0; b = m0 >> 8; }
      else     { m0 = (mtile - 64) * 16; X = a.Sf; Out = a.As; koff = 256; b = m0 >> 7; }
      int n0 = ntile * 64;

      f32x4 acc[4] = {};
#pragma unroll
      for (int ko = 0; ko < 256; ko += 32) {
        const float* row = X + (m0 + l15) * 256 + ko + quad * 8;
        f32x4 v0 = *(const f32x4*)(row);
        f32x4 v1 = *(const f32x4*)(row + 4);
        frag_u ah, al;
#pragma unroll
        for (int j = 0; j < 2; j++) {
          split2(v0[2 * j], v0[2 * j + 1], ah.u[j], al.u[j]);
          split2(v1[2 * j], v1[2 * j + 1], ah.u[2 + j], al.u[2 + j]);
        }
#pragma unroll
        for (int nt = 0; nt < 4; nt++) {
          int off = (n0 + nt * 16 + l15) * 512 + koff + ko + quad * 8;
          s16x8 bh = *(const s16x8*)(a.W0h + off);
          s16x8 bl = *(const s16x8*)(a.W0l + off);
          acc[nt] = __builtin_amdgcn_mfma_f32_16x16x32_bf16(ah.v, bh, acc[nt], 0, 0, 0);
          acc[nt] = __builtin_amdgcn_mfma_f32_16x16x32_bf16(al.v, bh, acc[nt], 0, 0, 0);
          acc[nt] = __builtin_amdgcn_mfma_f32_16x16x32_bf16(ah.v, bl, acc[nt], 0, 0, 0);
        }
      }
#pragma unroll
      for (int nt = 0; nt < 4; nt++) {
        int o = n0 + nt * 16 + l15;
        float bias = isQ ? 0.0f : a.b0[o];
        float cs = 0, cs2 = 0;
#pragma unroll
        for (int r = 0; r < 4; r++) {
          float y = acc[nt][r] + bias;
          Out[(m0 + quad * 4 + r) * 256 + o] = y;
          cs += y; cs2 += y * y;
        }
        cs  += __shfl_xor(cs, 16);  cs  += __shfl_xor(cs, 32);
        cs2 += __shfl_xor(cs2, 16); cs2 += __shfl_xor(cs2, 32);
        if (quad == 0) {
          int base = isQ ? 0 : 2048;
          atomicAdd(&a.ws0p[base + b * 256 + o], cs);       // <=48 adds/address
          atomicAdd(&a.ws0p[base + 1024 + b * 256 + o], cs2);
        }
      }
    }
  }
  gridbar(a.bar, 0);

  // ================= P2: BN0 finalize (redundant/block) -> LDS; 2 tiles; slots ws1p[bi]
  {
    int o = t;
    float sumY = 0, cross = 0, SQ2 = 0, SS2 = 0;
#pragma unroll
    for (int b = 0; b < 4; b++) {
      float sq1 = a.ws0p[b * 256 + o];
      float ss1 = a.ws0p[2048 + b * 256 + o];
      SQ2 += a.ws0p[1024 + b * 256 + o];
      SS2 += a.ws0p[3072 + b * 256 + o];
      sumY += 128.0f * sq1 + 256.0f * ss1;
      cross += sq1 * ss1;
    }
    float mean = sumY * INV_N;
    float var = (128.0f * SQ2 + 256.0f * SS2 + 2.0f * cross) * INV_N - mean * mean;
    float aa = a.g0[o] * rsqrtf(var + BN_EPS);
    sh_a0c0[o] = aa;
    sh_a0c0[256 + o] = a.bt0[o] - mean * aa;
  }
  if (t < 128) sh_s1[t] = 0.0f;
  __syncthreads();

  for (int T = bi; T < 512; T += NBLK) {
    int b_ = T >> 7, rem = T & 127, qt = rem >> 3, st = rem & 7;
    f32x4 acc[4][4] = {};
    mfma_kloop(a.Aq, a.As, sh_a0c0, a.W1h, a.W1l, b_, qt, st, w, l15, quad, acc);

#pragma unroll
    for (int nt = 0; nt < 4; nt++) {
      float bias = a.b1[nt * 16 + l15];
      float s = 0, s2 = 0;
#pragma unroll
      for (int mt = 0; mt < 4; mt++)
#pragma unroll
        for (int r = 0; r < 4; r++) {
          float y = acc[mt][nt][r] + bias;
          s += y; s2 += y * y;
        }
      s  += __shfl_xor(s, 16);  s  += __shfl_xor(s, 32);
      s2 += __shfl_xor(s2, 16); s2 += __shfl_xor(s2, 32);
      if (quad == 0) { red[0][w][nt][l15] = s; red[1][w][nt][l15] = s2; }
    }
    __syncthreads();
    if (t < 128) {
      int which = t >> 6, j = t & 63, nt = j >> 4, jl = j & 15;
      sh_s1[t] += red[which][0][nt][jl] + red[which][1][nt][jl] +
                  red[which][2][nt][jl] + red[which][3][nt][jl];
    }
    __syncthreads();
  }
  if (t < 128) a.ws1p[bi * 128 + t] = sh_s1[t];  // t<64: sum[j], t>=64: sumsq[j]
  gridbar(a.bar, 1);

  // ================= P3: BN1 finalize (redundant/block reduce of slots); 2 tiles; y2 + ws2p
  if (t < 128) {
    float accv = 0;
    for (int blk = 0; blk < NBLK; blk += 4)
      accv += a.ws1p[blk * 128 + t] + a.ws1p[(blk + 1) * 128 + t] +
              a.ws1p[(blk + 2) * 128 + t] + a.ws1p[(blk + 3) * 128 + t];
    sh_tot[t] = accv;
  }
  __syncthreads();
  if (t < 64) {
    float mean = sh_tot[t] * INV_N;
    float var = sh_tot[64 + t] * INV_N - mean * mean;
    float aa = a.g1[t] * rsqrtf(var + BN_EPS);
    sh_a1c1[t] = aa;
    sh_a1c1[64 + t] = a.bt1[t] - mean * aa;
  }
  __syncthreads();

  float gs = 0, gs2 = 0;  // block BN2 partials (t==0)
  for (int T = bi; T < 512; T += NBLK) {
    int b_ = T >> 7, rem = T & 127, qt = rem >> 3, st = rem & 7;
    f32x4 acc[4][4] = {};
    mfma_kloop(a.Aq, a.As, sh_a0c0, a.W1h, a.W1l, b_, qt, st, w, l15, quad, acc);

    float a1v[4], c1v[4], w2v[4], biasv[4];
#pragma unroll
    for (int nt = 0; nt < 4; nt++) {
      int j = nt * 16 + l15;
      a1v[nt] = sh_a1c1[j]; c1v[nt] = sh_a1c1[64 + j];
      w2v[nt] = a.W2[j]; biasv[nt] = a.b1[j];
    }
    float b2v = a.b2[0];
    float ls = 0, ls2 = 0;
#pragma unroll
    for (int mt = 0; mt < 4; mt++) {
      float part[4] = {0, 0, 0, 0};
#pragma unroll
      for (int nt = 0; nt < 4; nt++)
#pragma unroll
        for (int r = 0; r < 4; r++) {
          float y = acc[mt][nt][r] + biasv[nt];
          float z = fmaxf(a1v[nt] * y + c1v[nt], 0.0f);
          part[r] += z * w2v[nt];
        }
#pragma unroll
      for (int r = 0; r < 4; r++) {
        float p = part[r];
        p += __shfl_xor(p, 1); p += __shfl_xor(p, 2);
        p += __shfl_xor(p, 4); p += __shfl_xor(p, 8);
        part[r] = p + b2v;
      }
      if (l15 == 0) {
        int q = qt * 16 + w * 4 + mt;
        int P = ((b_ * 256 + q) * 128) + st * 16 + quad * 4;
        f32x4 o;
#pragma unroll
        for (int r = 0; r < 4; r++) { o[r] = part[r]; ls += part[r]; ls2 += part[r] * part[r]; }
        *(f32x4*)(a.y2 + P) = o;
      }
    }
    if (l15 == 0) { rs[t >> 4] = ls; rs2[t >> 4] = ls2; }
    __syncthreads();
    if (t == 0) {
#pragma unroll
      for (int i = 0; i < 16; i++) { gs += rs[i]; gs2 += rs2[i]; }
    }
    __syncthreads();
  }
  if (t == 0) { a.ws2p[bi * 2] = gs; a.ws2p[bi * 2 + 1] = gs2; }
  gridbar(a.bar, 2);

  // ================= P4: BN2 finalize (block-local tree over 256 slots); output
  {
    sh_r[t] = a.ws2p[2 * t];
    sh_q[t] = a.ws2p[2 * t + 1];
    __syncthreads();
    for (int off = 128; off; off >>= 1) {
      if (t < off) { sh_r[t] += sh_r[t + off]; sh_q[t] += sh_q[t + off]; }
      __syncthreads();
    }
    float mean = sh_r[0] * INV_N;
    float var = sh_q[0] * INV_N - mean * mean;
    float aa = a.g2[0] * rsqrtf(var + BN_EPS);
    float cc = a.bt2[0] - mean * aa;
    int gtid = bi * 256 + t;
    if (gtid < 32768) {
      f32x4 v = *(const f32x4*)(a.y2 + gtid * 4);
      f32x4 o;
#pragma unroll
      for (int r = 0; r < 4; r++) o[r] = fmaxf(aa * v[r] + cc, 0.0f);
      *(f32x4*)(a.out + gtid * 4) = o;
    }
  }
}

extern "C" void kernel_launch(void* const* d_in, const int* in_sizes, int n_in,
                              void* d_out, int out_size, void* d_ws, size_t ws_size,
                              hipStream_t stream)
{
  float* ws = (float*)d_ws;
  Args a;
  a.Sf  = (const float*)d_in[0];   // support [4,128,256]
  a.Qf  = (const float*)d_in[1];   // query   [4,256,256]
  a.W0  = (const float*)d_in[2];   // [256,512]
  a.b0  = (const float*)d_in[3];
  a.g0  = (const float*)d_in[4];
  a.bt0 = (const float*)d_in[5];
  a.W1  = (const float*)d_in[6];   // [64,256]
  a.b1  = (const float*)d_in[7];
  a.g1  = (const float*)d_in[8];
  a.bt1 = (const float*)d_in[9];
  a.W2  = (const float*)d_in[10];  // [1,64]
  a.b2  = (const float*)d_in[11];
  a.g2  = (const float*)d_in[12];
  a.bt2 = (const float*)d_in[13];

  a.Aq   = ws;                       // 262144 f
  a.As   = ws + 262144;              // 131072 f
  a.y2   = ws + 393216;              // 131072 f
  a.ws0p = ws + 524288;              // 4096 f (atomic accum)
  a.ws1p = ws + 528384;              // 256*128 = 32768 f (slots)
  a.ws2p = ws + 561152;              // 512 f (slots)
  a.bar  = (unsigned*)(ws + 561664); // 256 u32 (3 phases x 64)
  a.W0h  = (ushort*)(ws + 561920);   // 131072 u16 = 65536 f
  a.W0l  = (ushort*)(ws + 627456);   // 131072 u16
  a.W1h  = (ushort*)(ws + 692992);   // 16384 u16 = 8192 f
  a.W1l  = (ushort*)(ws + 701184);   // 16384 u16 -> total ~2.8 MB
  a.out  = (float*)d_out;

  k_prep<<<129, 256, 0, stream>>>(a.W0, a.W1, a.W0h, a.W0l, a.W1h, a.W1l,
                                  a.ws0p, a.bar);
  k_all<<<NBLK, 256, 0, stream>>>(a);
}